// Round 4
// baseline (486.573 us; speedup 1.0000x reference)
//
#include <hip/hip_runtime.h>

#define NTHREADS 256

__device__ __forceinline__ int reflect128(int p) {
    p = (p < 0) ? (-p - 1) : p;
    p = (p >= 128) ? (255 - p) : p;
    return p;
}

// Per output phase j: 3 consecutive nonzero taps out of 5.
// cc0/cs0 apply to the G0-pair source (Yl or lh), cc1/cs1 to the G1-pair (hl or hh).
__constant__ int   cs0[4] = {2, 1, 1, 0};
__constant__ int   cs1[4] = {1, 2, 0, 1};
__constant__ float cc0[4][3] = {
    { 0.760272369066126f, -0.0883294244510729f,  0.0351638365171441f},
    { 0.233890320607236f,  0.587518297723561f,  -0.114301837144249f},
    {-0.114301837144249f,  0.587518297723561f,   0.233890320607236f},
    { 0.0351638365171441f, -0.0883294244510729f, 0.760272369066126f}};
__constant__ float cc1[4][3] = {
    { 0.233890320607236f,  0.587518297723561f,  -0.114301837144249f},
    {-0.760272369066126f,  0.0883294244510729f, -0.0351638365171441f},
    {-0.0351638365171441f, 0.0883294244510729f, -0.760272369066126f},
    {-0.114301837144249f,  0.587518297723561f,   0.233890320607236f}};

__global__ __launch_bounds__(NTHREADS, 8)
void dtcwt_inv_kernel(const float* __restrict__ Yl,
                      const float* __restrict__ Yhr,
                      const float* __restrict__ Yhi,
                      float* __restrict__ out)
{
    const int tid = threadIdx.x;

    // XCD-aware swizzle (FETCH 224->66 MB). Each XCD gets a contiguous run of
    // gidx = whole planes, so a plane's 16 tiles share one L2.
    const int bid  = blockIdx.x;
    const int perx = gridDim.x >> 3;               // blocks per XCD (grid % 8 == 0)
    const int gidx = (bid & 7) * perx + (bid >> 3);
    const int plane = gidx >> 4;                   // 0..511
    const int tile  = gidx & 15;
    const int ct = tile & 3;                       // col tile 0..3
    const int rt = tile >> 2;                      // row tile 0..3

    const int OR0 = rt * 64, OC0 = ct * 64;
    const int i0r = OR0 >> 2, i0c = OC0 >> 2;
    const int yrb = 2 * i0r - 4;    // raw first y row of the 40-row window (even)
    const int icb = 2 * i0c - 4;    // raw first input col of the 40-col window (even)

    const float* yl = Yl + (size_t)plane * (128 * 128);
    const float* hr = Yhr + (size_t)plane * 6 * 4096;
    const float* hi = Yhi + (size_t)plane * 6 * 4096;

    // Staging (19.2 KB -> 8 blocks/CU):
    //   sLh[t][u]    = Lh        (y2's G0 taps, scalar b32, stride-2 reads = free)
    //   sQ [t][u]    = (Hl, Hh)  (y1/y2's G1 taps, float2)
    // Yl is NOT staged: read from global in the fused loop (L1/L2-resident window).
    __shared__ float  sLh[40][40];
    __shared__ float2 sQ[40][40];

    const float RS2 = 0.70710678118654752440f;  // 1/sqrt(2)

    // ---- Phase A: c2q staging; 2 statically-assigned quads/thread, all global
    //      loads issued before the dependent math (load ILP). ----
    {
        const int e0 = tid;              // always < 400
        const int e1 = tid + NTHREADS;   // valid for tid < 144
        const int has1 = (e1 < 400);

        const int t2a = e0 / 20, u2a = e0 - t2a * 20;
        const int ara = i0r - 2 + t2a, aca = i0c - 2 + u2a;
        const int oobra = (ara < 0) | (ara >= 64);
        const int oobca = (aca < 0) | (aca >= 64);
        const int r2a = oobra ? ((ara < 0) ? (-ara - 1) : (127 - ara)) : ara;
        const int c2a = oobca ? ((aca < 0) ? (-aca - 1) : (127 - aca)) : aca;
        const int offa = r2a * 64 + c2a;

        const int e1c = has1 ? e1 : 0;
        const int t2b = e1c / 20, u2b = e1c - t2b * 20;
        const int arb = i0r - 2 + t2b, acb = i0c - 2 + u2b;
        const int oobrb = (arb < 0) | (arb >= 64);
        const int oobcb = (acb < 0) | (acb >= 64);
        const int r2b = oobrb ? ((arb < 0) ? (-arb - 1) : (127 - arb)) : arb;
        const int c2b = oobcb ? ((acb < 0) ? (-acb - 1) : (127 - acb)) : acb;
        const int offb = r2b * 64 + c2b;

        float Ra[6], Ia[6], Rb[6], Ib[6];
#pragma unroll
        for (int k = 0; k < 6; ++k) { Ra[k] = hr[k * 4096 + offa]; Ia[k] = hi[k * 4096 + offa]; }
#pragma unroll
        for (int k = 0; k < 6; ++k) { Rb[k] = hr[k * 4096 + offb]; Ib[k] = hi[k * 4096 + offb]; }

#pragma unroll
        for (int wq = 0; wq < 2; ++wq) {
            if (wq == 1 && !has1) break;
            const float* R = (wq == 0) ? Ra : Rb;
            const float* I = (wq == 0) ? Ia : Ib;
            const int t2 = (wq == 0) ? t2a : t2b;
            const int u2 = (wq == 0) ? u2a : u2b;
            const int oobr = (wq == 0) ? oobra : oobrb;
            const int oobc = (wq == 0) ? oobca : oobcb;
#pragma unroll
            for (int dt = 0; dt < 2; ++dt) {
#pragma unroll
                for (int du = 0; du < 2; ++du) {
                    const int p = dt ^ oobr;            // reflection flips sample parity
                    const int q = du ^ oobc;
                    const float sA = (p & q) ? -RS2 : RS2;
                    const float sB = (p & (q ^ 1)) ? -RS2 : RS2;
                    float b0, b5, b2v, b3, b1, b4;
                    if (p == q) { b0 = R[0]; b5 = R[5]; b2v = R[2]; b3 = R[3]; b1 = R[1]; b4 = R[4]; }
                    else        { b0 = I[0]; b5 = I[5]; b2v = I[2]; b3 = I[3]; b1 = I[1]; b4 = I[4]; }
                    const int t = 2 * t2 + dt, u = 2 * u2 + du;
                    sLh[t][u] = sA * b0 + sB * b5;                       // Lh
                    sQ[t][u]  = make_float2(sA * b2v + sB * b3,          // Hl
                                            sA * b1 + sB * b4);          // Hh
                }
            }
        }
    }
    __syncthreads();

    // ---- Fused row+column filter: thread owns one column + 16-row output strip. ----
    const int c  = tid & 63;        // output column within tile
    const int g  = tid >> 6;        // 16-row output strip
    const int jc = c & 3;
    const int q2 = c >> 2;
    const float a0  = cc0[jc][0], a1  = cc0[jc][1], a2  = cc0[jc][2];
    const float b0w = cc1[jc][0], b1w = cc1[jc][1], b2w = cc1[jc][2];
    const int ub0 = 2 * q2 + (jc & 1) + 2 * cs0[jc];          // first G0 tap col (u)
    const int ub1 = 2 * q2 + ((jc & 1) ^ 1) + 2 * cs1[jc];    // first G1 tap col
    const int ic0 = reflect128(icb + ub0);                    // reflected global Yl cols
    const int ic1 = reflect128(icb + ub0 + 2);
    const int ic2 = reflect128(icb + ub0 + 4);

    const int tb = 8 * g;           // y rows needed: [tb+1, tb+14]
    float y1v[14], y2v[14];
#pragma unroll
    for (int k = 0; k < 14; ++k) {
        const int t = tb + 1 + k;
        const int ry = reflect128(yrb + t);
        const float* yrow = yl + ry * 128;
        const float2 Q0 = sQ[t][ub1], Q1 = sQ[t][ub1 + 2], Q2 = sQ[t][ub1 + 4];
        y1v[k] = yrow[ic0]   * a0  + yrow[ic1]       * a1  + yrow[ic2]       * a2
               + Q0.x        * b0w + Q1.x            * b1w + Q2.x            * b2w;
        y2v[k] = sLh[t][ub0] * a0  + sLh[t][ub0 + 2] * a1  + sLh[t][ub0 + 4] * a2
               + Q0.y        * b0w + Q1.y            * b1w + Q2.y            * b2w;
    }

    float* op = out + ((size_t)plane * 256 + OR0 + 16 * g) * 256 + OC0 + c;
#pragma unroll
    for (int j = 0; j < 4; ++j) {
        const int p0 = j & 1, p1 = p0 ^ 1;
        const int r0 = p0 + 2 * cs0[j];   // y1 tap rows: 2m + r0 + {0,2,4}
        const int r1 = p1 + 2 * cs1[j];
        const float d0 = cc0[j][0], d1 = cc0[j][1], d2 = cc0[j][2];
        const float e0 = cc1[j][0], e1 = cc1[j][1], e2 = cc1[j][2];
#pragma unroll
        for (int mm = 0; mm < 4; ++mm) {
            const int k0 = 2 * mm + r0 - 1;
            const int k1 = 2 * mm + r1 - 1;
            const float acc = y1v[k0] * d0 + y1v[k0 + 2] * d1 + y1v[k0 + 4] * d2
                            + y2v[k1] * e0 + y2v[k1 + 2] * e1 + y2v[k1 + 4] * e2;
            op[(size_t)(4 * mm + j) * 256] = acc;
        }
    }
}

extern "C" void kernel_launch(void* const* d_in, const int* in_sizes, int n_in,
                              void* d_out, int out_size, void* d_ws, size_t ws_size,
                              hipStream_t stream) {
    const float* Yl  = (const float*)d_in[0];
    const float* Yhr = (const float*)d_in[1];
    const float* Yhi = (const float*)d_in[2];
    float* out = (float*)d_out;

    const int planes = in_sizes[0] / (128 * 128);   // B*C = 512
    dim3 grid(planes * 16, 1, 1);
    dtcwt_inv_kernel<<<grid, NTHREADS, 0, stream>>>(Yl, Yhr, Yhi, out);
}

// Round 5
// 267.230 us; speedup vs baseline: 1.8208x; 1.8208x over previous
//
#include <hip/hip_runtime.h>

#define NTHREADS 256

__device__ __forceinline__ int reflect128(int p) {
    p = (p < 0) ? (-p - 1) : p;
    p = (p >= 128) ? (255 - p) : p;
    return p;
}

// Per output phase j: 3 consecutive nonzero taps out of 5.
// cc0/cs0 apply to the G0-pair source (Yl or lh), cc1/cs1 to the G1-pair (hl or hh).
__constant__ int   cs0[4] = {2, 1, 1, 0};
__constant__ int   cs1[4] = {1, 2, 0, 1};
__constant__ float cc0[4][3] = {
    { 0.760272369066126f, -0.0883294244510729f,  0.0351638365171441f},
    { 0.233890320607236f,  0.587518297723561f,  -0.114301837144249f},
    {-0.114301837144249f,  0.587518297723561f,   0.233890320607236f},
    { 0.0351638365171441f, -0.0883294244510729f, 0.760272369066126f}};
__constant__ float cc1[4][3] = {
    { 0.233890320607236f,  0.587518297723561f,  -0.114301837144249f},
    {-0.760272369066126f,  0.0883294244510729f, -0.0351638365171441f},
    {-0.0351638365171441f, 0.0883294244510729f, -0.760272369066126f},
    {-0.114301837144249f,  0.587518297723561f,   0.233890320607236f}};

// NOTE: min-waves hint 6 (NOT 8). Hint 8 capped the allocator at 32 VGPRs ->
// y1v/y2v spilled to scratch -> 870 MB of spill HBM traffic, 3.3x slowdown (round 4).
__global__ __launch_bounds__(NTHREADS, 6)
void dtcwt_inv_kernel(const float* __restrict__ Yl,
                      const float* __restrict__ Yhr,
                      const float* __restrict__ Yhi,
                      float* __restrict__ out)
{
    const int tid = threadIdx.x;

    // XCD-aware swizzle (FETCH 224->66 MB). Each XCD gets a contiguous run of
    // gidx = whole planes, so a plane's 16 tiles share one L2.
    const int bid  = blockIdx.x;
    const int perx = gridDim.x >> 3;               // blocks per XCD (grid % 8 == 0)
    const int gidx = (bid & 7) * perx + (bid >> 3);
    const int plane = gidx >> 4;                   // 0..511
    const int tile  = gidx & 15;
    const int ct = tile & 3;                       // col tile 0..3
    const int rt = tile >> 2;                      // row tile 0..3

    const int OR0 = rt * 64, OC0 = ct * 64;
    const int i0r = OR0 >> 2, i0c = OC0 >> 2;
    const int yrb = 2 * i0r - 4;    // raw first y row of the 40-row window (even)
    const int icb = 2 * i0c - 4;    // raw first input col of the 40-col window (even)

    const float* yl = Yl + (size_t)plane * (128 * 128);
    const float* hr = Yhr + (size_t)plane * 6 * 4096;
    const float* hi = Yhi + (size_t)plane * 6 * 4096;

    // Staging (19.2 KB -> LDS allows 8 blocks/CU):
    //   sLh[t][u]    = Lh        (y2's G0 taps, scalar b32, stride-2 reads = free)
    //   sQ [t][u]    = (Hl, Hh)  (y1/y2's G1 taps, float2)
    // Yl is NOT staged: read from global in the fused loop (L1/L2-resident window).
    __shared__ float  sLh[40][40];
    __shared__ float2 sQ[40][40];

    const float RS2 = 0.70710678118654752440f;  // 1/sqrt(2)

    // ---- Phase A: c2q staging; 2 statically-assigned quads/thread, all global
    //      loads issued before the dependent math (load ILP). ----
    {
        const int e0 = tid;              // always < 400
        const int e1 = tid + NTHREADS;   // valid for tid < 144
        const int has1 = (e1 < 400);

        const int t2a = e0 / 20, u2a = e0 - t2a * 20;
        const int ara = i0r - 2 + t2a, aca = i0c - 2 + u2a;
        const int oobra = (ara < 0) | (ara >= 64);
        const int oobca = (aca < 0) | (aca >= 64);
        const int r2a = oobra ? ((ara < 0) ? (-ara - 1) : (127 - ara)) : ara;
        const int c2a = oobca ? ((aca < 0) ? (-aca - 1) : (127 - aca)) : aca;
        const int offa = r2a * 64 + c2a;

        const int e1c = has1 ? e1 : 0;
        const int t2b = e1c / 20, u2b = e1c - t2b * 20;
        const int arb = i0r - 2 + t2b, acb = i0c - 2 + u2b;
        const int oobrb = (arb < 0) | (arb >= 64);
        const int oobcb = (acb < 0) | (acb >= 64);
        const int r2b = oobrb ? ((arb < 0) ? (-arb - 1) : (127 - arb)) : arb;
        const int c2b = oobcb ? ((acb < 0) ? (-acb - 1) : (127 - acb)) : acb;
        const int offb = r2b * 64 + c2b;

        float Ra[6], Ia[6], Rb[6], Ib[6];
#pragma unroll
        for (int k = 0; k < 6; ++k) { Ra[k] = hr[k * 4096 + offa]; Ia[k] = hi[k * 4096 + offa]; }
#pragma unroll
        for (int k = 0; k < 6; ++k) { Rb[k] = hr[k * 4096 + offb]; Ib[k] = hi[k * 4096 + offb]; }

#pragma unroll
        for (int wq = 0; wq < 2; ++wq) {
            if (wq == 1 && !has1) break;
            const float* R = (wq == 0) ? Ra : Rb;
            const float* I = (wq == 0) ? Ia : Ib;
            const int t2 = (wq == 0) ? t2a : t2b;
            const int u2 = (wq == 0) ? u2a : u2b;
            const int oobr = (wq == 0) ? oobra : oobrb;
            const int oobc = (wq == 0) ? oobca : oobcb;
#pragma unroll
            for (int dt = 0; dt < 2; ++dt) {
#pragma unroll
                for (int du = 0; du < 2; ++du) {
                    const int p = dt ^ oobr;            // reflection flips sample parity
                    const int q = du ^ oobc;
                    const float sA = (p & q) ? -RS2 : RS2;
                    const float sB = (p & (q ^ 1)) ? -RS2 : RS2;
                    float b0, b5, b2v, b3, b1, b4;
                    if (p == q) { b0 = R[0]; b5 = R[5]; b2v = R[2]; b3 = R[3]; b1 = R[1]; b4 = R[4]; }
                    else        { b0 = I[0]; b5 = I[5]; b2v = I[2]; b3 = I[3]; b1 = I[1]; b4 = I[4]; }
                    const int t = 2 * t2 + dt, u = 2 * u2 + du;
                    sLh[t][u] = sA * b0 + sB * b5;                       // Lh
                    sQ[t][u]  = make_float2(sA * b2v + sB * b3,          // Hl
                                            sA * b1 + sB * b4);          // Hh
                }
            }
        }
    }
    __syncthreads();

    // ---- Fused row+column filter: thread owns one column + 16-row output strip. ----
    const int c  = tid & 63;        // output column within tile
    const int g  = tid >> 6;        // 16-row output strip
    const int jc = c & 3;
    const int q2 = c >> 2;
    const float a0  = cc0[jc][0], a1  = cc0[jc][1], a2  = cc0[jc][2];
    const float b0w = cc1[jc][0], b1w = cc1[jc][1], b2w = cc1[jc][2];
    const int ub0 = 2 * q2 + (jc & 1) + 2 * cs0[jc];          // first G0 tap col (u)
    const int ub1 = 2 * q2 + ((jc & 1) ^ 1) + 2 * cs1[jc];    // first G1 tap col
    const int ic0 = reflect128(icb + ub0);                    // reflected global Yl cols
    const int ic1 = reflect128(icb + ub0 + 2);
    const int ic2 = reflect128(icb + ub0 + 4);

    const int tb = 8 * g;           // y rows needed: [tb+1, tb+14]
    float y1v[14], y2v[14];
#pragma unroll
    for (int k = 0; k < 14; ++k) {
        const int t = tb + 1 + k;
        const int ry = reflect128(yrb + t);
        const float* yrow = yl + ry * 128;
        const float2 Q0 = sQ[t][ub1], Q1 = sQ[t][ub1 + 2], Q2 = sQ[t][ub1 + 4];
        y1v[k] = yrow[ic0]   * a0  + yrow[ic1]       * a1  + yrow[ic2]       * a2
               + Q0.x        * b0w + Q1.x            * b1w + Q2.x            * b2w;
        y2v[k] = sLh[t][ub0] * a0  + sLh[t][ub0 + 2] * a1  + sLh[t][ub0 + 4] * a2
               + Q0.y        * b0w + Q1.y            * b1w + Q2.y            * b2w;
    }

    float* op = out + ((size_t)plane * 256 + OR0 + 16 * g) * 256 + OC0 + c;
#pragma unroll
    for (int j = 0; j < 4; ++j) {
        const int p0 = j & 1, p1 = p0 ^ 1;
        const int r0 = p0 + 2 * cs0[j];   // y1 tap rows: 2m + r0 + {0,2,4}
        const int r1 = p1 + 2 * cs1[j];
        const float d0 = cc0[j][0], d1 = cc0[j][1], d2 = cc0[j][2];
        const float e0 = cc1[j][0], e1 = cc1[j][1], e2 = cc1[j][2];
#pragma unroll
        for (int mm = 0; mm < 4; ++mm) {
            const int k0 = 2 * mm + r0 - 1;
            const int k1 = 2 * mm + r1 - 1;
            const float acc = y1v[k0] * d0 + y1v[k0 + 2] * d1 + y1v[k0 + 4] * d2
                            + y2v[k1] * e0 + y2v[k1 + 2] * e1 + y2v[k1 + 4] * e2;
            op[(size_t)(4 * mm + j) * 256] = acc;
        }
    }
}

extern "C" void kernel_launch(void* const* d_in, const int* in_sizes, int n_in,
                              void* d_out, int out_size, void* d_ws, size_t ws_size,
                              hipStream_t stream) {
    const float* Yl  = (const float*)d_in[0];
    const float* Yhr = (const float*)d_in[1];
    const float* Yhi = (const float*)d_in[2];
    float* out = (float*)d_out;

    const int planes = in_sizes[0] / (128 * 128);   // B*C = 512
    dim3 grid(planes * 16, 1, 1);
    dtcwt_inv_kernel<<<grid, NTHREADS, 0, stream>>>(Yl, Yhr, Yhi, out);
}